// Round 1
// baseline (474.561 us; speedup 1.0000x reference)
//
#include <hip/hip_runtime.h>

// Blur: depthwise separable 4x4 ([1,3,3,1] outer [1,3,3,1] / 64)
// input  (8,256,64,512) fp32, W wrap-pad 1, H reflect-pad 1
// output (8,256,63,511) fp32
// Memory-bound: ~532 MB compulsory traffic -> floor ~84us @ 6.3 TB/s.

constexpr int H_ = 64, W_ = 512;
constexpr int HO = 63, WO = 511;
constexpr int GROUPS = W_ / 4;  // 128 column-groups of 4 outputs each

// Horizontal blur of 4 consecutive outputs starting at col c0.
// Needs orig cols c0-1 .. c0+5 : p (wrap), A = [c0..c0+3], Bv = [c0+4,c0+5] (wrap for last group).
__device__ __forceinline__ float4 hblur_row(const float* __restrict__ row,
                                            int c0, int pcol, int bcol) {
    const float4 A  = *reinterpret_cast<const float4*>(row + c0);
    const float2 Bv = *reinterpret_cast<const float2*>(row + bcol);
    const float  p  = row[pcol];
    float4 r;
    r.x = fmaf(3.f, A.x + A.y, p   + A.z);   // 1*p  + 3*Ax + 3*Ay + 1*Az
    r.y = fmaf(3.f, A.y + A.z, A.x + A.w);
    r.z = fmaf(3.f, A.z + A.w, A.y + Bv.x);
    r.w = fmaf(3.f, A.w + Bv.x, A.z + Bv.y);
    return r;
}

__global__ __launch_bounds__(256) void blur_kernel(const float* __restrict__ h,
                                                   float* __restrict__ out) {
    const int tid = blockIdx.x * blockDim.x + threadIdx.x;
    const int g   = tid & (GROUPS - 1);   // column group 0..127
    const int bc  = tid >> 7;             // image index 0..2047

    const float* img = h   + (size_t)bc * (H_ * W_);
    float*       op  = out + (size_t)bc * (HO * WO);

    const int c0   = g * 4;
    const int pcol = (c0 - 1) & (W_ - 1);   // wrap left
    const int bcol = (c0 + 4) & (W_ - 1);   // wrap right (g=127: 512 -> 0)

    // Padded rows p=0..65 map to orig rows: p==0 -> 1, 1<=p<=64 -> p-1, p==65 -> 62 (reflect).
    float4 h0 = hblur_row(img + W_, c0, pcol, bcol);  // p=0 -> row 1
    float4 h1 = hblur_row(img,      c0, pcol, bcol);  // p=1 -> row 0
    float4 h2 = h0;                                   // p=2 -> row 1 (reuse)

    const int nstore = (g == GROUPS - 1) ? 3 : 4;     // out width 511: last group stores 3

    for (int oy = 0; oy < HO; ++oy) {
        const int p3 = oy + 3;                          // padded row index 3..65
        const int r  = (p3 <= H_) ? (p3 - 1) : (H_ - 2);
        const float4 h3 = hblur_row(img + r * W_, c0, pcol, bcol);

        float o[4];
        o[0] = (h0.x + h3.x + 3.f * (h1.x + h2.x)) * (1.f / 64.f);
        o[1] = (h0.y + h3.y + 3.f * (h1.y + h2.y)) * (1.f / 64.f);
        o[2] = (h0.z + h3.z + 3.f * (h1.z + h2.z)) * (1.f / 64.f);
        o[3] = (h0.w + h3.w + 3.f * (h1.w + h2.w)) * (1.f / 64.f);

        float* dst = op + oy * WO + c0;
        #pragma unroll
        for (int k = 0; k < 4; ++k)
            if (k < nstore) dst[k] = o[k];

        h0 = h1; h1 = h2; h2 = h3;
    }
}

extern "C" void kernel_launch(void* const* d_in, const int* in_sizes, int n_in,
                              void* d_out, int out_size, void* d_ws, size_t ws_size,
                              hipStream_t stream) {
    const float* h = (const float*)d_in[0];
    float* out = (float*)d_out;

    // 2048 images * 128 groups = 262144 threads
    const int total = 2048 * GROUPS;
    const int block = 256;
    const int grid  = total / block;  // 1024
    blur_kernel<<<grid, block, 0, stream>>>(h, out);
}